// Round 1
// baseline (431.788 us; speedup 1.0000x reference)
//
#include <hip/hip_runtime.h>
#include <math.h>

// Problem constants
#define NB    2048
#define KK    64
#define MM    64
#define DD    256
#define NITER 15
#define MITER 3
#define IEPS  20.0f   // 1/0.05

typedef __bf16 bf16_t;
typedef bf16_t bf16x8 __attribute__((ext_vector_type(8)));
typedef bf16_t bf16x4 __attribute__((ext_vector_type(4)));
typedef float  f32x16 __attribute__((ext_vector_type(16)));

#define XSTR 264   // bf16 elems per LDS activation row (256 + 8 pad)
#define CSTR 65    // f32 elems per LDS C/T row (64 + 1 pad)

// W workspace layout (fragment-native):
//   wf[layer*65536 + ((eb*16 + kc)*64 + lane)*8 + u]
//   = W[eb*32 + (lane&31)][kc*16 + (lane>>5)*8 + u]
// A wave's MFMA A-fragment load = 64 lanes x 16 B contiguous (1 KB burst).

__global__ __launch_bounds__(256) void convert_w_frag(const float* __restrict__ W1,
                                                      const float* __restrict__ W2,
                                                      bf16_t* __restrict__ wf) {
    const int j19 = blockIdx.x * 256 + threadIdx.x;   // grid 512 -> 131072
    const int layer = j19 >> 16;
    const int j = j19 & 65535;
    const int u    = j & 7;
    const int lane = (j >> 3) & 63;
    const int kc   = (j >> 9) & 15;
    const int eb   = j >> 13;
    const int l31  = lane & 31;
    const int lh   = lane >> 5;
    const int src  = (eb * 32 + l31) * 256 + kc * 16 + lh * 8 + u;
    wf[j19] = (bf16_t)(layer ? W2[src] : W1[src]);
}

// ---------------------------------------------------------------------------
// Fully fused kernel: one batch per block, 512 threads (8 waves).
// Wave wv owns feature slice e in [wv*32, wv*32+32) for both MLP layers.
// LDS Xs region is reused: X -> H -> f -> {Cs, Ts}.
// ---------------------------------------------------------------------------
__global__ __launch_bounds__(512, 4) void sinkhorn_all(
    const float* __restrict__ sq, const float* __restrict__ sr,
    const float* __restrict__ mq, const float* __restrict__ mr,
    const float* __restrict__ b1, const float* __restrict__ b2,
    const bf16_t* __restrict__ wf,
    float* __restrict__ out) {

    __shared__ __align__(16) char smem[128 * XSTR * 2];   // 67584 B
    bf16_t* Xs = (bf16_t*)smem;
    float*  Cs = (float*)smem;                      // overlay after f is dead
    float*  Ts = (float*)(smem + 64 * CSTR * 4);
    __shared__ float nrm[128];
    __shared__ float lmq_s[64], lmr_s[64], la_s[64], lb_s[64];
    __shared__ float b1_s[256], b2_s[256];
    __shared__ float red_s[8];

    const int b  = blockIdx.x;
    const int t  = threadIdx.x;
    const int ln = t & 63;
    const int wv = t >> 6;          // 0..7
    const int l31 = ln & 31;
    const int lh  = ln >> 5;

    // ---- Phase 0: stage X = [sq_b ; sr_b] fp32 -> bf16, max load ILP ----
    {
        const float4* sq4 = (const float4*)(sq + (size_t)b * 64 * 256);
        const float4* sr4 = (const float4*)(sr + (size_t)b * 64 * 256);
        float4 xr[16];
        #pragma unroll
        for (int it = 0; it < 16; ++it) {
            const int r = wv + it * 8;          // wave-uniform row 0..127
            xr[it] = (r < 64) ? sq4[r * 64 + ln] : sr4[(r - 64) * 64 + ln];
        }
        #pragma unroll
        for (int it = 0; it < 16; ++it) {
            const int r = wv + it * 8;
            bf16x4 p;
            p[0] = (bf16_t)xr[it].x; p[1] = (bf16_t)xr[it].y;
            p[2] = (bf16_t)xr[it].z; p[3] = (bf16_t)xr[it].w;
            *(bf16x4*)&Xs[(size_t)r * XSTR + ln * 4] = p;
        }
        if (t < 256) b1_s[t] = b1[t];
        else         b2_s[t - 256] = b2[t - 256];
        if (t >= 256) {
            const int u = t - 256;               // 0..255
            if (u < 64)        lmq_s[u]       = __logf(fmaxf(mq[(size_t)b * 64 + u], 1e-8f));
            else if (u < 128)  lmr_s[u - 64]  = __logf(fmaxf(mr[(size_t)b * 64 + (u - 64)], 1e-8f));
            else if (u < 192)  lb_s[u - 128]  = 0.0f;
        }
    }
    __syncthreads();

    // ---- Phase 1: layer 1, H -> hreg ----
    bf16x4 hreg[2][2][4];   // [half][z][g]
    {
        const bf16_t* wbase = wf + ((size_t)wv * 16) * 512 + ln * 8;
        f32x16 acc[2][2];
        #pragma unroll
        for (int i = 0; i < 16; ++i) {
            acc[0][0][i] = 0.0f; acc[0][1][i] = 0.0f;
            acc[1][0][i] = 0.0f; acc[1][1][i] = 0.0f;
        }
        #pragma unroll
        for (int kg = 0; kg < 2; ++kg) {
            bf16x8 af[8];
            #pragma unroll
            for (int u = 0; u < 8; ++u)
                af[u] = *(const bf16x8*)(wbase + (size_t)(kg * 8 + u) * 512);
            #pragma unroll
            for (int half = 0; half < 2; ++half) {
                const bf16_t* x0 = Xs + (size_t)(half * 64 + l31) * XSTR + lh * 8;
                const bf16_t* x1 = x0 + 32 * XSTR;
                #pragma unroll
                for (int u = 0; u < 8; ++u) {
                    const int kc = kg * 8 + u;
                    bf16x8 bx0 = *(const bf16x8*)(x0 + kc * 16);
                    bf16x8 bx1 = *(const bf16x8*)(x1 + kc * 16);
                    acc[half][0] = __builtin_amdgcn_mfma_f32_32x32x16_bf16(af[u], bx0, acc[half][0], 0, 0, 0);
                    acc[half][1] = __builtin_amdgcn_mfma_f32_32x32x16_bf16(af[u], bx1, acc[half][1], 0, 0, 0);
                }
            }
        }
        const int e0 = wv * 32;
        #pragma unroll
        for (int half = 0; half < 2; ++half)
            #pragma unroll
            for (int z = 0; z < 2; ++z)
                #pragma unroll
                for (int g = 0; g < 4; ++g) {
                    const int e = e0 + 8 * g + 4 * lh;
                    #pragma unroll
                    for (int rr = 0; rr < 4; ++rr) {
                        float v = acc[half][z][4 * g + rr] + b1_s[e + rr];
                        hreg[half][z][g][rr] = (bf16_t)fmaxf(v, 0.0f);
                    }
                }
    }
    __syncthreads();             // all waves done reading X

    // ---- write H over Xs ----
    {
        const int e0 = wv * 32;
        #pragma unroll
        for (int half = 0; half < 2; ++half)
            #pragma unroll
            for (int z = 0; z < 2; ++z) {
                const int n = half * 64 + z * 32 + l31;
                #pragma unroll
                for (int g = 0; g < 4; ++g)
                    *(bf16x4*)&Xs[(size_t)n * XSTR + e0 + 8 * g + 4 * lh] = hreg[half][z][g];
            }
    }
    __syncthreads();

    // ---- Phase 2: layer 2, f -> hreg, then overwrite Xs ----
    {
        const bf16_t* wbase = wf + 65536 + ((size_t)wv * 16) * 512 + ln * 8;
        f32x16 acc[2][2];
        #pragma unroll
        for (int i = 0; i < 16; ++i) {
            acc[0][0][i] = 0.0f; acc[0][1][i] = 0.0f;
            acc[1][0][i] = 0.0f; acc[1][1][i] = 0.0f;
        }
        #pragma unroll
        for (int kg = 0; kg < 2; ++kg) {
            bf16x8 af[8];
            #pragma unroll
            for (int u = 0; u < 8; ++u)
                af[u] = *(const bf16x8*)(wbase + (size_t)(kg * 8 + u) * 512);
            #pragma unroll
            for (int half = 0; half < 2; ++half) {
                const bf16_t* x0 = Xs + (size_t)(half * 64 + l31) * XSTR + lh * 8;
                const bf16_t* x1 = x0 + 32 * XSTR;
                #pragma unroll
                for (int u = 0; u < 8; ++u) {
                    const int kc = kg * 8 + u;
                    bf16x8 bx0 = *(const bf16x8*)(x0 + kc * 16);
                    bf16x8 bx1 = *(const bf16x8*)(x1 + kc * 16);
                    acc[half][0] = __builtin_amdgcn_mfma_f32_32x32x16_bf16(af[u], bx0, acc[half][0], 0, 0, 0);
                    acc[half][1] = __builtin_amdgcn_mfma_f32_32x32x16_bf16(af[u], bx1, acc[half][1], 0, 0, 0);
                }
            }
        }
        const int e0 = wv * 32;
        #pragma unroll
        for (int half = 0; half < 2; ++half)
            #pragma unroll
            for (int z = 0; z < 2; ++z)
                #pragma unroll
                for (int g = 0; g < 4; ++g) {
                    const int e = e0 + 8 * g + 4 * lh;
                    #pragma unroll
                    for (int rr = 0; rr < 4; ++rr)
                        hreg[half][z][g][rr] = (bf16_t)(acc[half][z][4 * g + rr] + b2_s[e + rr]);
                }
    }
    __syncthreads();             // all waves done reading H

    {
        const int e0 = wv * 32;
        #pragma unroll
        for (int half = 0; half < 2; ++half)
            #pragma unroll
            for (int z = 0; z < 2; ++z) {
                const int n = half * 64 + z * 32 + l31;
                #pragma unroll
                for (int g = 0; g < 4; ++g)
                    *(bf16x4*)&Xs[(size_t)n * XSTR + e0 + 8 * g + 4 * lh] = hreg[half][z][g];
            }
    }
    __syncthreads();             // f now fully in Xs

    // ---- Phase 3: row norms ||f||^2  (512 threads: 4 per row) ----
    {
        const int r = t >> 2;
        const int q = t & 3;
        const bf16_t* frow = &Xs[(size_t)r * XSTR + q * 64];
        float s = 0.0f;
        #pragma unroll
        for (int c = 0; c < 8; ++c) {
            bf16x8 v = *(const bf16x8*)(frow + c * 8);
            #pragma unroll
            for (int u = 0; u < 8; ++u) { float f = (float)v[u]; s = fmaf(f, f, s); }
        }
        s += __shfl_xor(s, 1);
        s += __shfl_xor(s, 2);
        if (q == 0) nrm[r] = s;
    }
    __syncthreads();

    // ---- Phase 4: cdist (waves 0..3), C -> regs + global ----
    float cvv[16];
    int qbase = 0, mcol = 0;
    if (wv < 4) {
        const int qt = wv >> 1, rt = wv & 1;
        const bf16_t* qa = &Xs[(size_t)(qt * 32 + l31) * XSTR + lh * 8];
        const bf16_t* ra = &Xs[(size_t)(64 + rt * 32 + l31) * XSTR + lh * 8];
        f32x16 acc;
        #pragma unroll
        for (int i = 0; i < 16; ++i) acc[i] = 0.0f;
        #pragma unroll
        for (int kc = 0; kc < 16; ++kc) {
            bf16x8 av = *(const bf16x8*)(qa + kc * 16);
            bf16x8 bv = *(const bf16x8*)(ra + kc * 16);
            acc = __builtin_amdgcn_mfma_f32_32x32x16_bf16(av, bv, acc, 0, 0, 0);
        }
        mcol  = rt * 32 + l31;
        qbase = qt * 32;
        const float nr_m = nrm[64 + mcol];
        float* outC = out + 2048 + (size_t)2048 * 4096 + (size_t)b * 4096;
        #pragma unroll
        for (int g = 0; g < 4; ++g) {
            #pragma unroll
            for (int rr = 0; rr < 4; ++rr) {
                const int q = qbase + 8 * g + 4 * lh + rr;
                float d2 = nrm[q] + nr_m - 2.0f * acc[4 * g + rr];
                float cv = sqrtf(fmaxf(d2, 0.0f));
                cvv[4 * g + rr] = cv;
                outC[q * 64 + mcol] = cv;
            }
        }
    }
    __syncthreads();             // Fs dead everywhere; overlay Cs
    if (wv < 4) {
        #pragma unroll
        for (int g = 0; g < 4; ++g)
            #pragma unroll
            for (int rr = 0; rr < 4; ++rr)
                Cs[(qbase + 8 * g + 4 * lh + rr) * CSTR + mcol] = cvv[4 * g + rr];
    }
    __syncthreads();

    // ---- Phase 5: Sinkhorn (512 threads: 8 per row, 8 elems each) ----
    const int ki = t >> 3;      // 0..63
    const int jj = t & 7;       // strip of 8
    float rowV[8], colV[8];
    #pragma unroll
    for (int i = 0; i < 8; ++i) {
        const int m2 = jj * 8 + i;
        rowV[i] = fmaf(Cs[ki * CSTR + m2], -IEPS, lmr_s[m2]);
        colV[i] = fmaf(Cs[m2 * CSTR + ki], -IEPS, lmq_s[m2]);
    }
    const float lmq_k = lmq_s[ki];
    const float lmr_m = lmr_s[ki];

    for (int it = 0; it < NITER; ++it) {
        float mx = -1e30f;
        #pragma unroll
        for (int i = 0; i < 8; ++i) mx = fmaxf(mx, rowV[i] + lb_s[jj * 8 + i]);
        mx = fmaxf(mx, __shfl_xor(mx, 1));
        mx = fmaxf(mx, __shfl_xor(mx, 2));
        mx = fmaxf(mx, __shfl_xor(mx, 4));
        float s = 0.0f;
        #pragma unroll
        for (int i = 0; i < 8; ++i) s += __expf(rowV[i] + lb_s[jj * 8 + i] - mx);
        s += __shfl_xor(s, 1);
        s += __shfl_xor(s, 2);
        s += __shfl_xor(s, 4);
        if (jj == 0) la_s[ki] = -(lmq_k + mx + __logf(s));
        __syncthreads();

        mx = -1e30f;
        #pragma unroll
        for (int i = 0; i < 8; ++i) mx = fmaxf(mx, colV[i] + la_s[jj * 8 + i]);
        mx = fmaxf(mx, __shfl_xor(mx, 1));
        mx = fmaxf(mx, __shfl_xor(mx, 2));
        mx = fmaxf(mx, __shfl_xor(mx, 4));
        float s2 = 0.0f;
        #pragma unroll
        for (int i = 0; i < 8; ++i) s2 += __expf(colV[i] + la_s[jj * 8 + i] - mx);
        s2 += __shfl_xor(s2, 1);
        s2 += __shfl_xor(s2, 2);
        s2 += __shfl_xor(s2, 4);
        if (jj == 0) lb_s[ki] = -(lmr_m + mx + __logf(s2));
        __syncthreads();
    }

    // ---- Phase 6: T = exp(lK + la + lb) ----
    {
        const float base = lmq_k + la_s[ki];
        #pragma unroll
        for (int i = 0; i < 8; ++i) {
            const int m2 = jj * 8 + i;
            Ts[ki * CSTR + m2] = __expf(rowV[i] + lb_s[m2] + base);
        }
    }
    __syncthreads();

    // ---- Phase 7: power iterations ----
    for (int pi = 0; pi < MITER; ++pi) {
        float vv[8], rs = 0.0f;
        #pragma unroll
        for (int i = 0; i < 8; ++i) {
            float v = Ts[ki * CSTR + jj * 8 + i];
            v = v * v; vv[i] = v; rs += v;
        }
        rs += __shfl_xor(rs, 1); rs += __shfl_xor(rs, 2); rs += __shfl_xor(rs, 4);
        float inv = 1.0f / (rs + 1e-8f);
        #pragma unroll
        for (int i = 0; i < 8; ++i) Ts[ki * CSTR + jj * 8 + i] = vv[i] * inv;
        __syncthreads();

        float cs = 0.0f;
        #pragma unroll
        for (int i = 0; i < 8; ++i) { float v = Ts[(jj * 8 + i) * CSTR + ki]; vv[i] = v; cs += v; }
        cs += __shfl_xor(cs, 1); cs += __shfl_xor(cs, 2); cs += __shfl_xor(cs, 4);
        inv = 1.0f / (cs + 1e-8f);
        #pragma unroll
        for (int i = 0; i < 8; ++i) Ts[(jj * 8 + i) * CSTR + ki] = vv[i] * inv;
        __syncthreads();
    }

    // ---- Phase 8: write T, c = sum(T*C), sigmoid(-c) ----
    {
        float part = 0.0f;
        float tq[8];
        #pragma unroll
        for (int i = 0; i < 8; ++i) {
            const int m2 = jj * 8 + i;
            float tv = Ts[ki * CSTR + m2];
            tq[i] = tv;
            part = fmaf(tv, Cs[ki * CSTR + m2], part);
        }
        float* outT = out + 2048 + (size_t)b * 4096 + ki * 64 + jj * 8;
        ((float4*)outT)[0] = make_float4(tq[0], tq[1], tq[2], tq[3]);
        ((float4*)outT)[1] = make_float4(tq[4], tq[5], tq[6], tq[7]);
        #pragma unroll
        for (int off = 1; off < 64; off <<= 1) part += __shfl_xor(part, off);
        if (ln == 0) red_s[wv] = part;
    }
    __syncthreads();
    if (t == 0) {
        float c = 0.0f;
        #pragma unroll
        for (int w = 0; w < 8; ++w) c += red_s[w];
        out[2048 + (size_t)2 * 2048 * 4096 + b] = c;
        out[b] = 1.0f / (1.0f + __expf(c));
    }
}

extern "C" void kernel_launch(void* const* d_in, const int* in_sizes, int n_in,
                              void* d_out, int out_size, void* d_ws, size_t ws_size,
                              hipStream_t stream) {
    const float* sq = (const float*)d_in[0];
    const float* sr = (const float*)d_in[1];
    const float* mq = (const float*)d_in[2];
    const float* mr = (const float*)d_in[3];
    const float* W1 = (const float*)d_in[4];
    const float* b1 = (const float*)d_in[5];
    const float* W2 = (const float*)d_in[6];
    const float* b2 = (const float*)d_in[7];

    bf16_t* wf = (bf16_t*)d_ws;   // 131072 bf16 = 256 KB (ws is >=134 MB in practice)

    convert_w_frag<<<512, 256, 0, stream>>>(W1, W2, wf);
    sinkhorn_all<<<NB, 512, 0, stream>>>(sq, sr, mq, mr, b1, b2, wf, (float*)d_out);
}

// Round 2
// 419.164 us; speedup vs baseline: 1.0301x; 1.0301x over previous
//
#include <hip/hip_runtime.h>
#include <math.h>

// Problem constants
#define NB    2048
#define KK    64
#define MM    64
#define DD    256
#define NITER 15
#define MITER 3
#define IEPS  20.0f   // 1/0.05

typedef __bf16 bf16_t;
typedef bf16_t bf16x8 __attribute__((ext_vector_type(8)));
typedef bf16_t bf16x4 __attribute__((ext_vector_type(4)));
typedef float  f32x16 __attribute__((ext_vector_type(16)));

#define XSTR 264   // bf16 elems per LDS activation row (256 + 8 pad)
#define CSTR 65    // f32 elems per LDS C/T row (64 + 1 pad)

// W workspace layout (fragment-native):
//   wf[layer*65536 + ((eb*16 + kc)*64 + lane)*8 + u]
//   = W[eb*32 + (lane&31)][kc*16 + (lane>>5)*8 + u]

__global__ __launch_bounds__(256) void convert_w_frag(const float* __restrict__ W1,
                                                      const float* __restrict__ W2,
                                                      bf16_t* __restrict__ wf) {
    const int j19 = blockIdx.x * 256 + threadIdx.x;   // grid 512 -> 131072
    const int layer = j19 >> 16;
    const int j = j19 & 65535;
    const int u    = j & 7;
    const int lane = (j >> 3) & 63;
    const int kc   = (j >> 9) & 15;
    const int eb   = j >> 13;
    const int l31  = lane & 31;
    const int lh   = lane >> 5;
    const int src  = (eb * 32 + l31) * 256 + kc * 16 + lh * 8 + u;
    wf[j19] = (bf16_t)(layer ? W2[src] : W1[src]);
}

// ---------------------------------------------------------------------------
// Kernel A: MLP (2 layers) + cdist, writes C to global. One batch per block,
// 512 threads (8 waves). Wave wv owns feature slice [wv*32, wv*32+32).
// LDS Xs region is reused: X -> H -> f.  No Sinkhorn state -> shorter block.
// ---------------------------------------------------------------------------
__global__ __launch_bounds__(512, 4) void mlp_cdist(
    const float* __restrict__ sq, const float* __restrict__ sr,
    const float* __restrict__ b1, const float* __restrict__ b2,
    const bf16_t* __restrict__ wf,
    float* __restrict__ out) {

    __shared__ __align__(16) char smem[128 * XSTR * 2];   // 67584 B
    bf16_t* Xs = (bf16_t*)smem;
    __shared__ float nrm[128];
    __shared__ float b1_s[256], b2_s[256];

    const int b  = blockIdx.x;
    const int t  = threadIdx.x;
    const int ln = t & 63;
    const int wv = t >> 6;          // 0..7
    const int l31 = ln & 31;
    const int lh  = ln >> 5;

    // ---- Phase 0: stage X = [sq_b ; sr_b] fp32 -> bf16 ----
    {
        const float4* sq4 = (const float4*)(sq + (size_t)b * 64 * 256);
        const float4* sr4 = (const float4*)(sr + (size_t)b * 64 * 256);
        float4 xr[16];
        #pragma unroll
        for (int it = 0; it < 16; ++it) {
            const int r = wv + it * 8;          // wave-uniform row 0..127
            xr[it] = (r < 64) ? sq4[r * 64 + ln] : sr4[(r - 64) * 64 + ln];
        }
        #pragma unroll
        for (int it = 0; it < 16; ++it) {
            const int r = wv + it * 8;
            bf16x4 p;
            p[0] = (bf16_t)xr[it].x; p[1] = (bf16_t)xr[it].y;
            p[2] = (bf16_t)xr[it].z; p[3] = (bf16_t)xr[it].w;
            *(bf16x4*)&Xs[(size_t)r * XSTR + ln * 4] = p;
        }
        if (t < 256) b1_s[t] = b1[t];
        else         b2_s[t - 256] = b2[t - 256];
    }
    __syncthreads();

    // ---- Phase 1: layer 1, H -> hreg ----
    bf16x4 hreg[2][2][4];   // [half][z][g]
    {
        const bf16_t* wbase = wf + ((size_t)wv * 16) * 512 + ln * 8;
        f32x16 acc[2][2];
        #pragma unroll
        for (int i = 0; i < 16; ++i) {
            acc[0][0][i] = 0.0f; acc[0][1][i] = 0.0f;
            acc[1][0][i] = 0.0f; acc[1][1][i] = 0.0f;
        }
        #pragma unroll
        for (int kg = 0; kg < 2; ++kg) {
            bf16x8 af[8];
            #pragma unroll
            for (int u = 0; u < 8; ++u)
                af[u] = *(const bf16x8*)(wbase + (size_t)(kg * 8 + u) * 512);
            #pragma unroll
            for (int half = 0; half < 2; ++half) {
                const bf16_t* x0 = Xs + (size_t)(half * 64 + l31) * XSTR + lh * 8;
                const bf16_t* x1 = x0 + 32 * XSTR;
                #pragma unroll
                for (int u = 0; u < 8; ++u) {
                    const int kc = kg * 8 + u;
                    bf16x8 bx0 = *(const bf16x8*)(x0 + kc * 16);
                    bf16x8 bx1 = *(const bf16x8*)(x1 + kc * 16);
                    acc[half][0] = __builtin_amdgcn_mfma_f32_32x32x16_bf16(af[u], bx0, acc[half][0], 0, 0, 0);
                    acc[half][1] = __builtin_amdgcn_mfma_f32_32x32x16_bf16(af[u], bx1, acc[half][1], 0, 0, 0);
                }
            }
        }
        const int e0 = wv * 32;
        #pragma unroll
        for (int half = 0; half < 2; ++half)
            #pragma unroll
            for (int z = 0; z < 2; ++z)
                #pragma unroll
                for (int g = 0; g < 4; ++g) {
                    const int e = e0 + 8 * g + 4 * lh;
                    #pragma unroll
                    for (int rr = 0; rr < 4; ++rr) {
                        float v = acc[half][z][4 * g + rr] + b1_s[e + rr];
                        hreg[half][z][g][rr] = (bf16_t)fmaxf(v, 0.0f);
                    }
                }
    }
    __syncthreads();             // all waves done reading X

    // ---- write H over Xs ----
    {
        const int e0 = wv * 32;
        #pragma unroll
        for (int half = 0; half < 2; ++half)
            #pragma unroll
            for (int z = 0; z < 2; ++z) {
                const int n = half * 64 + z * 32 + l31;
                #pragma unroll
                for (int g = 0; g < 4; ++g)
                    *(bf16x4*)&Xs[(size_t)n * XSTR + e0 + 8 * g + 4 * lh] = hreg[half][z][g];
            }
    }
    __syncthreads();

    // ---- Phase 2: layer 2, f -> hreg ----
    {
        const bf16_t* wbase = wf + 65536 + ((size_t)wv * 16) * 512 + ln * 8;
        f32x16 acc[2][2];
        #pragma unroll
        for (int i = 0; i < 16; ++i) {
            acc[0][0][i] = 0.0f; acc[0][1][i] = 0.0f;
            acc[1][0][i] = 0.0f; acc[1][1][i] = 0.0f;
        }
        #pragma unroll
        for (int kg = 0; kg < 2; ++kg) {
            bf16x8 af[8];
            #pragma unroll
            for (int u = 0; u < 8; ++u)
                af[u] = *(const bf16x8*)(wbase + (size_t)(kg * 8 + u) * 512);
            #pragma unroll
            for (int half = 0; half < 2; ++half) {
                const bf16_t* x0 = Xs + (size_t)(half * 64 + l31) * XSTR + lh * 8;
                const bf16_t* x1 = x0 + 32 * XSTR;
                #pragma unroll
                for (int u = 0; u < 8; ++u) {
                    const int kc = kg * 8 + u;
                    bf16x8 bx0 = *(const bf16x8*)(x0 + kc * 16);
                    bf16x8 bx1 = *(const bf16x8*)(x1 + kc * 16);
                    acc[half][0] = __builtin_amdgcn_mfma_f32_32x32x16_bf16(af[u], bx0, acc[half][0], 0, 0, 0);
                    acc[half][1] = __builtin_amdgcn_mfma_f32_32x32x16_bf16(af[u], bx1, acc[half][1], 0, 0, 0);
                }
            }
        }
        const int e0 = wv * 32;
        #pragma unroll
        for (int half = 0; half < 2; ++half)
            #pragma unroll
            for (int z = 0; z < 2; ++z)
                #pragma unroll
                for (int g = 0; g < 4; ++g) {
                    const int e = e0 + 8 * g + 4 * lh;
                    #pragma unroll
                    for (int rr = 0; rr < 4; ++rr)
                        hreg[half][z][g][rr] = (bf16_t)(acc[half][z][4 * g + rr] + b2_s[e + rr]);
                }
    }
    __syncthreads();             // all waves done reading H

    {
        const int e0 = wv * 32;
        #pragma unroll
        for (int half = 0; half < 2; ++half)
            #pragma unroll
            for (int z = 0; z < 2; ++z) {
                const int n = half * 64 + z * 32 + l31;
                #pragma unroll
                for (int g = 0; g < 4; ++g)
                    *(bf16x4*)&Xs[(size_t)n * XSTR + e0 + 8 * g + 4 * lh] = hreg[half][z][g];
            }
    }
    __syncthreads();             // f now fully in Xs

    // ---- Phase 3: row norms ||f||^2  (512 threads: 4 per row) ----
    {
        const int r = t >> 2;
        const int q = t & 3;
        const bf16_t* frow = &Xs[(size_t)r * XSTR + q * 64];
        float s = 0.0f;
        #pragma unroll
        for (int c = 0; c < 8; ++c) {
            bf16x8 v = *(const bf16x8*)(frow + c * 8);
            #pragma unroll
            for (int u = 0; u < 8; ++u) { float f = (float)v[u]; s = fmaf(f, f, s); }
        }
        s += __shfl_xor(s, 1);
        s += __shfl_xor(s, 2);
        if (q == 0) nrm[r] = s;
    }
    __syncthreads();

    // ---- Phase 4: cdist (waves 0..3), C -> global ----
    if (wv < 4) {
        const int qt = wv >> 1, rt = wv & 1;
        const bf16_t* qa = &Xs[(size_t)(qt * 32 + l31) * XSTR + lh * 8];
        const bf16_t* ra = &Xs[(size_t)(64 + rt * 32 + l31) * XSTR + lh * 8];
        f32x16 acc;
        #pragma unroll
        for (int i = 0; i < 16; ++i) acc[i] = 0.0f;
        #pragma unroll
        for (int kc = 0; kc < 16; ++kc) {
            bf16x8 av = *(const bf16x8*)(qa + kc * 16);
            bf16x8 bv = *(const bf16x8*)(ra + kc * 16);
            acc = __builtin_amdgcn_mfma_f32_32x32x16_bf16(av, bv, acc, 0, 0, 0);
        }
        const int mcol  = rt * 32 + l31;
        const int qbase = qt * 32;
        const float nr_m = nrm[64 + mcol];
        float* outC = out + 2048 + (size_t)2048 * 4096 + (size_t)b * 4096;
        #pragma unroll
        for (int g = 0; g < 4; ++g) {
            #pragma unroll
            for (int rr = 0; rr < 4; ++rr) {
                const int q = qbase + 8 * g + 4 * lh + rr;
                float d2 = nrm[q] + nr_m - 2.0f * acc[4 * g + rr];
                outC[q * 64 + mcol] = sqrtf(fmaxf(d2, 0.0f));
            }
        }
    }
}

// ---------------------------------------------------------------------------
// Kernel B: Sinkhorn + power iterations + outputs, from C in global.
// LDS 34.3 KB -> 4 blocks/CU; __launch_bounds__(512,8) caps VGPR at 64
// -> 32 waves/CU (full occupancy) to hide the barrier-chain latency.
// ---------------------------------------------------------------------------
__global__ __launch_bounds__(512, 8) void sinkhorn_from_C(
    const float* __restrict__ mq, const float* __restrict__ mr,
    float* __restrict__ out) {

    __shared__ float Cs[64 * CSTR];
    __shared__ float Ts[64 * CSTR];
    __shared__ float lmq_s[64], lmr_s[64], la_s[64], lb_s[64];
    __shared__ float red_s[8];

    const int b  = blockIdx.x;
    const int t  = threadIdx.x;
    const int ln = t & 63;
    const int wv = t >> 6;
    const int ki = t >> 3;      // 0..63 (row)
    const int jj = t & 7;       // strip of 8 cols

    // ---- stage C (each thread owns row ki, cols jj*8..jj*8+7) ----
    const float* Cg = out + 2048 + (size_t)2048 * 4096 + (size_t)b * 4096 + ki * 64 + jj * 8;
    const float4 c0 = ((const float4*)Cg)[0];
    const float4 c1 = ((const float4*)Cg)[1];

    if (t < 64)        lmq_s[t]       = __logf(fmaxf(mq[(size_t)b * 64 + t], 1e-8f));
    else if (t < 128)  lmr_s[t - 64]  = __logf(fmaxf(mr[(size_t)b * 64 + (t - 64)], 1e-8f));
    else if (t < 192)  lb_s[t - 128]  = 0.0f;

    {
        float* cr = &Cs[ki * CSTR + jj * 8];
        cr[0] = c0.x; cr[1] = c0.y; cr[2] = c0.z; cr[3] = c0.w;
        cr[4] = c1.x; cr[5] = c1.y; cr[6] = c1.z; cr[7] = c1.w;
    }
    __syncthreads();

    // ---- Sinkhorn init: rowV from regs, colV via LDS transpose ----
    float rowV[8], colV[8];
    {
        const float cv[8] = {c0.x, c0.y, c0.z, c0.w, c1.x, c1.y, c1.z, c1.w};
        #pragma unroll
        for (int i = 0; i < 8; ++i)
            rowV[i] = fmaf(cv[i], -IEPS, lmr_s[jj * 8 + i]);
        #pragma unroll
        for (int i = 0; i < 8; ++i)
            colV[i] = fmaf(Cs[(jj * 8 + i) * CSTR + ki], -IEPS, lmq_s[jj * 8 + i]);
    }
    const float lmq_k = lmq_s[ki];
    const float lmr_m = lmr_s[ki];

    for (int it = 0; it < NITER; ++it) {
        float mx = -1e30f;
        #pragma unroll
        for (int i = 0; i < 8; ++i) mx = fmaxf(mx, rowV[i] + lb_s[jj * 8 + i]);
        mx = fmaxf(mx, __shfl_xor(mx, 1));
        mx = fmaxf(mx, __shfl_xor(mx, 2));
        mx = fmaxf(mx, __shfl_xor(mx, 4));
        float s = 0.0f;
        #pragma unroll
        for (int i = 0; i < 8; ++i) s += __expf(rowV[i] + lb_s[jj * 8 + i] - mx);
        s += __shfl_xor(s, 1);
        s += __shfl_xor(s, 2);
        s += __shfl_xor(s, 4);
        if (jj == 0) la_s[ki] = -(lmq_k + mx + __logf(s));
        __syncthreads();

        mx = -1e30f;
        #pragma unroll
        for (int i = 0; i < 8; ++i) mx = fmaxf(mx, colV[i] + la_s[jj * 8 + i]);
        mx = fmaxf(mx, __shfl_xor(mx, 1));
        mx = fmaxf(mx, __shfl_xor(mx, 2));
        mx = fmaxf(mx, __shfl_xor(mx, 4));
        float s2 = 0.0f;
        #pragma unroll
        for (int i = 0; i < 8; ++i) s2 += __expf(colV[i] + la_s[jj * 8 + i] - mx);
        s2 += __shfl_xor(s2, 1);
        s2 += __shfl_xor(s2, 2);
        s2 += __shfl_xor(s2, 4);
        if (jj == 0) lb_s[ki] = -(lmr_m + mx + __logf(s2));
        __syncthreads();
    }

    // ---- T = exp(lK + la + lb) ----
    {
        const float base = lmq_k + la_s[ki];
        #pragma unroll
        for (int i = 0; i < 8; ++i) {
            const int m2 = jj * 8 + i;
            Ts[ki * CSTR + m2] = __expf(rowV[i] + lb_s[m2] + base);
        }
    }
    __syncthreads();

    // ---- power iterations ----
    for (int pi = 0; pi < MITER; ++pi) {
        float vv[8], rs = 0.0f;
        #pragma unroll
        for (int i = 0; i < 8; ++i) {
            float v = Ts[ki * CSTR + jj * 8 + i];
            v = v * v; vv[i] = v; rs += v;
        }
        rs += __shfl_xor(rs, 1); rs += __shfl_xor(rs, 2); rs += __shfl_xor(rs, 4);
        float inv = 1.0f / (rs + 1e-8f);
        #pragma unroll
        for (int i = 0; i < 8; ++i) Ts[ki * CSTR + jj * 8 + i] = vv[i] * inv;
        __syncthreads();

        float cs = 0.0f;
        #pragma unroll
        for (int i = 0; i < 8; ++i) { float v = Ts[(jj * 8 + i) * CSTR + ki]; vv[i] = v; cs += v; }
        cs += __shfl_xor(cs, 1); cs += __shfl_xor(cs, 2); cs += __shfl_xor(cs, 4);
        inv = 1.0f / (cs + 1e-8f);
        #pragma unroll
        for (int i = 0; i < 8; ++i) Ts[(jj * 8 + i) * CSTR + ki] = vv[i] * inv;
        __syncthreads();
    }

    // ---- write T, c = sum(T*C), sigmoid(-c) ----
    {
        float part = 0.0f;
        float tq[8];
        #pragma unroll
        for (int i = 0; i < 8; ++i) {
            const int m2 = jj * 8 + i;
            float tv = Ts[ki * CSTR + m2];
            tq[i] = tv;
            part = fmaf(tv, Cs[ki * CSTR + m2], part);
        }
        float* outT = out + 2048 + (size_t)b * 4096 + ki * 64 + jj * 8;
        ((float4*)outT)[0] = make_float4(tq[0], tq[1], tq[2], tq[3]);
        ((float4*)outT)[1] = make_float4(tq[4], tq[5], tq[6], tq[7]);
        #pragma unroll
        for (int off = 1; off < 64; off <<= 1) part += __shfl_xor(part, off);
        if (ln == 0) red_s[wv] = part;
    }
    __syncthreads();
    if (t == 0) {
        float c = 0.0f;
        #pragma unroll
        for (int w = 0; w < 8; ++w) c += red_s[w];
        out[2048 + (size_t)2 * 2048 * 4096 + b] = c;
        out[b] = 1.0f / (1.0f + __expf(c));
    }
}

extern "C" void kernel_launch(void* const* d_in, const int* in_sizes, int n_in,
                              void* d_out, int out_size, void* d_ws, size_t ws_size,
                              hipStream_t stream) {
    const float* sq = (const float*)d_in[0];
    const float* sr = (const float*)d_in[1];
    const float* mq = (const float*)d_in[2];
    const float* mr = (const float*)d_in[3];
    const float* W1 = (const float*)d_in[4];
    const float* b1 = (const float*)d_in[5];
    const float* W2 = (const float*)d_in[6];
    const float* b2 = (const float*)d_in[7];

    bf16_t* wf = (bf16_t*)d_ws;   // 131072 bf16 = 256 KB

    convert_w_frag<<<512, 256, 0, stream>>>(W1, W2, wf);
    mlp_cdist<<<NB, 512, 0, stream>>>(sq, sr, b1, b2, wf, (float*)d_out);
    sinkhorn_from_C<<<NB, 512, 0, stream>>>(mq, mr, (float*)d_out);
}